// Round 3
// baseline (759.163 us; speedup 1.0000x reference)
//
#include <hip/hip_runtime.h>

#define E_TOT 262144
#define EPB   64        // edges per K1 block
#define NB1   4096      // E_TOT / EPB
#define G_TOT 1024
#define BN_EPS 1e-5f

using f32x4   = __attribute__((ext_vector_type(4))) float;
using bf16x8  = __attribute__((ext_vector_type(8))) __bf16;
using ushort8 = __attribute__((ext_vector_type(8))) unsigned short;

static __device__ __forceinline__ unsigned short f2bf(float x) {
    union { float f; unsigned u; } v; v.f = x;
    unsigned r = v.u + 0x7FFFu + ((v.u >> 16) & 1u);   // RTNE
    return (unsigned short)(r >> 16);
}
static __device__ __forceinline__ float bf2f(unsigned short h) {
    union { unsigned u; float f; } v; v.u = ((unsigned)h) << 16;
    return v.f;
}
// packed f32x2 -> bf16x2 (RTNE), lo in bits[15:0]
static __device__ __forceinline__ unsigned cvtpk(float lo, float hi) {
    unsigned r;
    asm("v_cvt_pk_bf16_f32 %0, %1, %2" : "=v"(r) : "v"(lo), "v"(hi));
    return r;
}

// ---------------------------------------------------------------------------
// K0: pack 5 weight matrices (f32 [K][128] row-major) into bf16 MFMA
// B-fragment order for mfma_f32_16x16x32_bf16 (16B contiguous per lane).
// ---------------------------------------------------------------------------
__global__ __launch_bounds__(256) void k0_pack(
        const float* __restrict__ wea, const float* __restrict__ wer,
        const float* __restrict__ web, const float* __restrict__ wfr,
        const float* __restrict__ wfb, unsigned short* __restrict__ out)
{
    int idx = blockIdx.x * 256 + threadIdx.x;   // 0 .. 147455
    const float* src; unsigned short* dst; int li;
    if      (idx < 16384) { src = wea; dst = out;          li = idx;          }
    else if (idx < 32768) { src = wer; dst = out + 16384;  li = idx - 16384;  }
    else if (idx < 49152) { src = web; dst = out + 32768;  li = idx - 32768;  }
    else if (idx < 98304) { src = wfr; dst = out + 49152;  li = idx - 49152;  }
    else                  { src = wfb; dst = out + 98304;  li = idx - 98304;  }
    int j    = li & 7;
    int lane = (li >> 3) & 63;
    int tile = li >> 9;
    int nt = tile & 7, kt = tile >> 3;
    int k = kt * 32 + (lane >> 4) * 8 + j;
    int n = nt * 16 + (lane & 15);
    dst[li] = f2bf(src[k * 128 + n]);
}

// ---------------------------------------------------------------------------
// K1: fused edge MLP. 64 edges/block, 8 waves (512 thr), 64 KB LDS.
// 2 blocks/CU -> 16 waves/CU (4/SIMD) for latency hiding.
// Stage 1: wave w -> matrix m=w>>1, n-half hn=w&1. mt=4 (all 64 rows),
//          4 n-tiles: 16 MFMAs per 4 B-loads, half the weight matrix per
//          wave -> per-block weight traffic unchanged vs 4-wave version.
// Stage 2: wave w owns 2 n-tiles (32 h-cols) over K=384, mt=4.
// Epilogue: h staged to LDS, coalesced dwordx4 stores; BN partials
// block-contiguous (pt[blk*512 + c]).
// ---------------------------------------------------------------------------
__global__ __launch_bounds__(512, 4) void k1_edges(
        const float* __restrict__ atom, const float* __restrict__ rdf,
        const float* __restrict__ bdf,
        const float* __restrict__ b_ea, const float* __restrict__ b_er,
        const float* __restrict__ b_eb, const float* __restrict__ b_fr,
        const float* __restrict__ b_fb,
        const ushort8* __restrict__ wpea, const ushort8* __restrict__ wper,
        const ushort8* __restrict__ wpeb, const ushort8* __restrict__ wpfr,
        const ushort8* __restrict__ wpfb,
        unsigned short* __restrict__ hout, float* __restrict__ pt)
{
    __shared__ unsigned short lds[EPB * 512];   // 64 KB

    const int tid  = threadIdx.x;
    const int w    = tid >> 6;        // 0..7
    const int lane = tid & 63;
    const int l16  = lane & 15;
    const int q    = lane >> 4;
    const int blk  = blockIdx.x;
    const int e0   = blk * EPB;

    // ---- stage 1: matrix m = w>>1, n-half hn = w&1 -------------------------
    const int m  = w >> 1;
    const int hn = w & 1;
    const float* src; int stride; const ushort8* wp; const float* bias; bool r6;
    if      (m == 0) { src = atom;        stride = 256; wp = wpea; bias = b_ea; r6 = false; }
    else if (m == 1) { src = atom + 128;  stride = 256; wp = wpea; bias = b_ea; r6 = false; }
    else if (m == 2) { src = rdf;         stride = 128; wp = wper; bias = b_er; r6 = true;  }
    else             { src = bdf;         stride = 128; wp = wpeb; bias = b_eb; r6 = true;  }

    bf16x8 af[4][4];   // [m-tile][k-tile] A fragments: A[m=l16][k=q*8+j]
#pragma unroll
    for (int mt = 0; mt < 4; ++mt) {
        const float* rp = src + (size_t)(e0 + mt * 16 + l16) * stride + q * 8;
#pragma unroll
        for (int kt = 0; kt < 4; ++kt) {
            const float4* p = (const float4*)(rp + kt * 32);
            float4 x0 = p[0], x1 = p[1];
            uint4 u;
            u.x = cvtpk(x0.x, x0.y); u.y = cvtpk(x0.z, x0.w);
            u.z = cvtpk(x1.x, x1.y); u.w = cvtpk(x1.z, x1.w);
            af[mt][kt] = __builtin_bit_cast(bf16x8, u);
        }
    }

    const float lim = r6 ? 6.0f : 3.4e38f;
#pragma unroll
    for (int ntl = 0; ntl < 4; ++ntl) {
        const int nt = hn * 4 + ntl;
        bf16x8 bfr[4];
#pragma unroll
        for (int kt = 0; kt < 4; ++kt)
            bfr[kt] = __builtin_bit_cast(bf16x8, wp[(kt * 8 + nt) * 64 + lane]);
        float bv = bias[nt * 16 + l16];
        f32x4 acc[4];
#pragma unroll
        for (int mt = 0; mt < 4; ++mt) acc[mt] = (f32x4){bv, bv, bv, bv};
#pragma unroll
        for (int kt = 0; kt < 4; ++kt)
#pragma unroll
            for (int mt = 0; mt < 4; ++mt)
                acc[mt] = __builtin_amdgcn_mfma_f32_16x16x32_bf16(af[mt][kt], bfr[kt], acc[mt], 0, 0, 0);
        // activation + swizzled LDS store (C layout: row=q*4+r, col=l16)
        int colc = m * 128 + nt * 16 + l16;
        int c8 = colc >> 3, c7 = colc & 7;
#pragma unroll
        for (int mt = 0; mt < 4; ++mt) {
#pragma unroll
            for (int r = 0; r < 4; ++r) {
                float v = __builtin_amdgcn_fmed3f(acc[mt][r], 0.0f, lim);
                int row = mt * 16 + q * 4 + r;
                lds[(row << 9) + ((c8 ^ (row & 7)) << 3) + c7] = f2bf(v);
            }
        }
    }
    __syncthreads();

    // ---- stage 2: h = [inter(0:384)]@W_fr | [inter(0:256,384:512)]@W_fb ----
    const ushort8* wp2   = (w < 4) ? wpfr : wpfb;
    const float*   bias2 = (w < 4) ? b_fr : b_fb;
    const int nb = (w & 3) * 2;          // this wave's 2 n-tiles within its matrix

    f32x4 acc2[2][4];                    // [ntl][mt]
#pragma unroll
    for (int ntl = 0; ntl < 2; ++ntl) {
        float bv = bias2[(nb + ntl) * 16 + l16];
#pragma unroll
        for (int mt = 0; mt < 4; ++mt) acc2[ntl][mt] = (f32x4){bv, bv, bv, bv};
    }

#pragma unroll
    for (int kt = 0; kt < 12; ++kt) {
        int colbase = (w < 4) ? kt * 32 : (kt < 8 ? kt * 32 : 384 + (kt - 8) * 32);
        int c8b = colbase >> 3;
        bf16x8 a[4];
#pragma unroll
        for (int mt = 0; mt < 4; ++mt) {
            int row = mt * 16 + l16;
            a[mt] = *(const bf16x8*)&lds[(row << 9) + (((c8b + q) ^ (row & 7)) << 3)];
        }
        bf16x8 bfr2[2];
#pragma unroll
        for (int ntl = 0; ntl < 2; ++ntl)
            bfr2[ntl] = __builtin_bit_cast(bf16x8, wp2[(kt * 8 + nb + ntl) * 64 + lane]);
#pragma unroll
        for (int ntl = 0; ntl < 2; ++ntl)
#pragma unroll
            for (int mt = 0; mt < 4; ++mt)
                acc2[ntl][mt] = __builtin_amdgcn_mfma_f32_16x16x32_bf16(a[mt], bfr2[ntl], acc2[ntl][mt], 0, 0, 0);
    }
    __syncthreads();   // everyone done reading stage-1 LDS before reuse

    // ---- epilogue A: stage h into LDS (xor-16 bank swizzle) + BN partials --
    const int colb = (w >> 2) * 128 + (w & 3) * 32;
#pragma unroll
    for (int ntl = 0; ntl < 2; ++ntl) {
        int c = colb + ntl * 16 + l16;
        float s = 0.0f, sq = 0.0f;
#pragma unroll
        for (int mt = 0; mt < 4; ++mt) {
#pragma unroll
            for (int r = 0; r < 4; ++r) {
                float v = acc2[ntl][mt][r];
                int row = mt * 16 + q * 4 + r;
                lds[(row << 8) + (c ^ ((row & 4) << 2))] = f2bf(v);
                s += v; sq += v * v;
            }
        }
        s  += __shfl_xor(s, 16);  s  += __shfl_xor(s, 32);
        sq += __shfl_xor(sq, 16); sq += __shfl_xor(sq, 32);
        if (q == 0) {
            pt[(size_t)blk * 512 + c]       = s;
            pt[(size_t)blk * 512 + 256 + c] = sq;
        }
    }
    __syncthreads();

    // ---- epilogue B: coalesced h writes (4 x dwordx4 per thread) -----------
#pragma unroll
    for (int i = 0; i < 4; ++i) {
        int idx  = i * 512 + tid;         // chunk of 8 ushorts
        int row  = idx >> 5;
        int cb   = (idx & 31) * 8;
        int phys = (row << 8) + (cb ^ ((row & 4) << 2));
        uint4 v = *(const uint4*)&lds[phys];
        *(uint4*)(hout + (((size_t)(e0 + row)) << 8) + cb) = v;
    }
}

// ---------------------------------------------------------------------------
// K2a: coalesced partial reduction of pt rows. Block b sums 64 rows for all
// 512 columns (threads read consecutive floats). pt2[b*512 + t].
// ---------------------------------------------------------------------------
__global__ __launch_bounds__(256) void k2a_reduce(
        const float* __restrict__ pt, float* __restrict__ pt2)
{
    int b = blockIdx.x, t = threadIdx.x;
    const float* base = pt + (size_t)b * 64 * 512;
    float s0 = 0.0f, s1 = 0.0f;
    for (int r = 0; r < 64; ++r) {
        s0 += base[r * 512 + t];
        s1 += base[r * 512 + 256 + t];
    }
    pt2[b * 512 + t]       = s0;
    pt2[b * 512 + 256 + t] = s1;
}

// ---------------------------------------------------------------------------
// K2b: finalize BN affine (scale, shift) from 64 partial rows.
// ---------------------------------------------------------------------------
__global__ __launch_bounds__(256) void k2b_stats(
        const float* __restrict__ pt2, const float* __restrict__ gamma,
        const float* __restrict__ beta, float* __restrict__ stats)
{
    int c = threadIdx.x;   // single block, 256 threads
    float S = 0.0f, Q = 0.0f;
    for (int i = 0; i < 64; ++i) {
        S += pt2[i * 512 + c];
        Q += pt2[i * 512 + 256 + c];
    }
    float mu  = S / (float)E_TOT;
    float var = Q / (float)E_TOT - mu * mu;
    float sc  = gamma[c] * rsqrtf(var + BN_EPS);
    stats[c]       = sc;
    stats[256 + c] = beta[c] - mu * sc;
}

// ---------------------------------------------------------------------------
// K3: per-graph BN-apply + relu + mean-pool + MLP(257->16->1) -> out[g]
// Lanes load uint4 (8 cols); 8 rows in flight per block iteration.
// ---------------------------------------------------------------------------
__global__ __launch_bounds__(256) void k3_pool(
        const unsigned short* __restrict__ h, const int* __restrict__ gidx,
        const float* __restrict__ ref, const float* __restrict__ stats,
        const float* __restrict__ W1, const float* __restrict__ b1,
        const float* __restrict__ W2, const float* __restrict__ b2,
        float* __restrict__ out)
{
    int g = blockIdx.x, tid = threadIdx.x;
    int w = tid >> 6, lane = tid & 63;
    // lower_bound(g), lower_bound(g+1) on sorted graph_idx
    int lo = 0, hi = E_TOT;
    while (lo < hi) { int m = (lo + hi) >> 1; if (gidx[m] < g) lo = m + 1; else hi = m; }
    int start = lo;
    hi = E_TOT;
    while (lo < hi) { int m = (lo + hi) >> 1; if (gidx[m] < g + 1) lo = m + 1; else hi = m; }
    int end = lo;

    int half = lane >> 5;
    int c0   = (lane & 31) * 8;
    float sc[8], sh[8], acc[8];
#pragma unroll
    for (int j = 0; j < 8; ++j) {
        sc[j] = stats[c0 + j]; sh[j] = stats[256 + c0 + j]; acc[j] = 0.0f;
    }

    for (int r = start + w * 2 + half; r < end; r += 8) {
        uint4 v = *(const uint4*)(h + (((size_t)r) << 8) + c0);
        unsigned u[4] = {v.x, v.y, v.z, v.w};
#pragma unroll
        for (int j = 0; j < 4; ++j) {
            float f0 = bf2f((unsigned short)(u[j] & 0xffff));
            float f1 = bf2f((unsigned short)(u[j] >> 16));
            acc[2 * j]     += fmaxf(fmaf(f0, sc[2 * j],     sh[2 * j]),     0.0f);
            acc[2 * j + 1] += fmaxf(fmaf(f1, sc[2 * j + 1], sh[2 * j + 1]), 0.0f);
        }
    }
#pragma unroll
    for (int j = 0; j < 8; ++j) acc[j] += __shfl_xor(acc[j], 32);

    __shared__ float part[4 * 256];
    __shared__ float sp[256];
    if (half == 0) {
#pragma unroll
        for (int j = 0; j < 8; ++j) part[w * 256 + c0 + j] = acc[j];
    }
    __syncthreads();

    int n = end - start;
    float inv = 1.0f / fmaxf((float)n, 1.0f);
    sp[tid] = (part[tid] + part[256 + tid] + part[512 + tid] + part[768 + tid]) * inv;
    __syncthreads();

    if (tid < 16) {
        float z = b1[tid] + ref[g] * W1[256 * 16 + tid];
        for (int c = 0; c < 256; ++c) z = fmaf(sp[c], W1[c * 16 + tid], z);
        z = fmaxf(z, 0.0f);
        float t = z * W2[tid];
        t += __shfl_xor(t, 1); t += __shfl_xor(t, 2);
        t += __shfl_xor(t, 4); t += __shfl_xor(t, 8);
        if (tid == 0) out[g] = fmaxf(t + b2[0], 0.0f);
    }
}

// ---------------------------------------------------------------------------
// Workspace layout (bytes):
//   [0)         packed bf16 weights: 147456 * 2        = 294912
//   [294912)    h: E*256 bf16                          = 134217728
//   [134512640) pt: 4096*512 f32 partials              = 8388608
//   [142901248) pt2: 64*512 f32 partials               = 131072  (in old pt region)
//   [151289856) stats: 512 f32                         = 2048
// ---------------------------------------------------------------------------
extern "C" void kernel_launch(void* const* d_in, const int* in_sizes, int n_in,
                              void* d_out, int out_size, void* d_ws, size_t ws_size,
                              hipStream_t stream)
{
    (void)in_sizes; (void)n_in; (void)out_size; (void)ws_size;
    const float* atom  = (const float*)d_in[0];
    const float* rdf   = (const float*)d_in[1];
    const float* bdf   = (const float*)d_in[2];
    const int*   gidx  = (const int*)d_in[6];
    const float* ref   = (const float*)d_in[7];
    const float* Wea   = (const float*)d_in[8];  const float* bea = (const float*)d_in[9];
    const float* Wer   = (const float*)d_in[10]; const float* ber = (const float*)d_in[11];
    const float* Web   = (const float*)d_in[12]; const float* beb = (const float*)d_in[13];
    const float* Wfr   = (const float*)d_in[14]; const float* bfr = (const float*)d_in[15];
    const float* Wfb   = (const float*)d_in[16]; const float* bfb = (const float*)d_in[17];
    const float* gamma = (const float*)d_in[18]; const float* beta = (const float*)d_in[19];
    const float* W1    = (const float*)d_in[20]; const float* b1  = (const float*)d_in[21];
    const float* W2    = (const float*)d_in[22]; const float* b2  = (const float*)d_in[23];

    char* ws = (char*)d_ws;
    unsigned short* wpack = (unsigned short*)ws;
    unsigned short* h     = (unsigned short*)(ws + 294912);
    float*          pt    = (float*)(ws + 134512640);
    float*          pt2   = (float*)(ws + 142901248);
    float*          stats = (float*)(ws + 151289856);

    k0_pack<<<576, 256, 0, stream>>>(Wea, Wer, Web, Wfr, Wfb, wpack);
    k1_edges<<<NB1, 512, 0, stream>>>(atom, rdf, bdf, bea, ber, beb, bfr, bfb,
            (const ushort8*)wpack,
            (const ushort8*)(wpack + 16384),
            (const ushort8*)(wpack + 32768),
            (const ushort8*)(wpack + 49152),
            (const ushort8*)(wpack + 98304),
            h, pt);
    k2a_reduce<<<64, 256, 0, stream>>>(pt, pt2);
    k2b_stats<<<1, 256, 0, stream>>>(pt2, gamma, beta, stats);
    k3_pool<<<G_TOT, 256, 0, stream>>>(h, gidx, ref, stats, W1, b1, W2, b2, (float*)d_out);
}

// Round 4
// 668.788 us; speedup vs baseline: 1.1351x; 1.1351x over previous
//
#include <hip/hip_runtime.h>

#define E_TOT 262144
#define EPB   64        // edges per K1 block
#define NB1   4096      // E_TOT / EPB
#define G_TOT 1024
#define BN_EPS 1e-5f

using f32x4   = __attribute__((ext_vector_type(4))) float;
using bf16x8  = __attribute__((ext_vector_type(8))) __bf16;
using ushort8 = __attribute__((ext_vector_type(8))) unsigned short;

static __device__ __forceinline__ unsigned short f2bf(float x) {
    union { float f; unsigned u; } v; v.f = x;
    unsigned r = v.u + 0x7FFFu + ((v.u >> 16) & 1u);   // RTNE
    return (unsigned short)(r >> 16);
}
static __device__ __forceinline__ float bf2f(unsigned short h) {
    union { unsigned u; float f; } v; v.u = ((unsigned)h) << 16;
    return v.f;
}
// packed f32x2 -> bf16x2 (RTNE), lo in bits[15:0]
static __device__ __forceinline__ unsigned cvtpk(float lo, float hi) {
    unsigned r;
    asm("v_cvt_pk_bf16_f32 %0, %1, %2" : "=v"(r) : "v"(lo), "v"(hi));
    return r;
}

// ---------------------------------------------------------------------------
// K0: pack 5 weight matrices (f32 [K][128] row-major) into bf16 MFMA
// B-fragment order for mfma_f32_16x16x32_bf16 (16B contiguous per lane).
// ---------------------------------------------------------------------------
__global__ __launch_bounds__(256) void k0_pack(
        const float* __restrict__ wea, const float* __restrict__ wer,
        const float* __restrict__ web, const float* __restrict__ wfr,
        const float* __restrict__ wfb, unsigned short* __restrict__ out)
{
    int idx = blockIdx.x * 256 + threadIdx.x;   // 0 .. 147455
    const float* src; unsigned short* dst; int li;
    if      (idx < 16384) { src = wea; dst = out;          li = idx;          }
    else if (idx < 32768) { src = wer; dst = out + 16384;  li = idx - 16384;  }
    else if (idx < 49152) { src = web; dst = out + 32768;  li = idx - 32768;  }
    else if (idx < 98304) { src = wfr; dst = out + 49152;  li = idx - 49152;  }
    else                  { src = wfb; dst = out + 98304;  li = idx - 98304;  }
    int j    = li & 7;
    int lane = (li >> 3) & 63;
    int tile = li >> 9;
    int nt = tile & 7, kt = tile >> 3;
    int k = kt * 32 + (lane >> 4) * 8 + j;
    int n = nt * 16 + (lane & 15);
    dst[li] = f2bf(src[k * 128 + n]);
}

// ---------------------------------------------------------------------------
// K1: fused edge MLP. 64 edges/block, 8 waves (512 thr), 64 KB LDS.
// 2 blocks/CU -> 16 waves/CU (4/SIMD).
// Stage 1: wave w -> matrix m=w>>1, ROW-half mh=w&1 (rows mh*32..+31).
//          af[2][4] = 32 VGPRs (m-split, not n-split, to avoid the round-3
//          scratch spill); all 8 n-tiles per wave. A-reads disjoint across
//          waves; weight reads duplicated x2 (L1/L2-resident, cheap).
// Stage 2: wave w owns 2 n-tiles (32 h-cols) over K=384, mt=4.
// Epilogue: h staged to LDS, coalesced dwordx4 stores; BN partials
// block-contiguous (pt[blk*512 + c]).
// ---------------------------------------------------------------------------
__global__ __launch_bounds__(512, 4) void k1_edges(
        const float* __restrict__ atom, const float* __restrict__ rdf,
        const float* __restrict__ bdf,
        const float* __restrict__ b_ea, const float* __restrict__ b_er,
        const float* __restrict__ b_eb, const float* __restrict__ b_fr,
        const float* __restrict__ b_fb,
        const ushort8* __restrict__ wpea, const ushort8* __restrict__ wper,
        const ushort8* __restrict__ wpeb, const ushort8* __restrict__ wpfr,
        const ushort8* __restrict__ wpfb,
        unsigned short* __restrict__ hout, float* __restrict__ pt)
{
    __shared__ unsigned short lds[EPB * 512];   // 64 KB

    const int tid  = threadIdx.x;
    const int w    = tid >> 6;        // 0..7
    const int lane = tid & 63;
    const int l16  = lane & 15;
    const int q    = lane >> 4;
    const int blk  = blockIdx.x;
    const int e0   = blk * EPB;

    // ---- stage 1: matrix m = w>>1, row-half mh = w&1 -----------------------
    const int m  = w >> 1;
    const int mh = w & 1;
    const float* src; int stride; const ushort8* wp; const float* bias; bool r6;
    if      (m == 0) { src = atom;        stride = 256; wp = wpea; bias = b_ea; r6 = false; }
    else if (m == 1) { src = atom + 128;  stride = 256; wp = wpea; bias = b_ea; r6 = false; }
    else if (m == 2) { src = rdf;         stride = 128; wp = wper; bias = b_er; r6 = true;  }
    else             { src = bdf;         stride = 128; wp = wpeb; bias = b_eb; r6 = true;  }

    bf16x8 af[2][4];   // [m-tile][k-tile] A fragments: A[row=mh*32+mt*16+l16][k=q*8+j]
#pragma unroll
    for (int mt = 0; mt < 2; ++mt) {
        const float* rp = src + (size_t)(e0 + mh * 32 + mt * 16 + l16) * stride + q * 8;
#pragma unroll
        for (int kt = 0; kt < 4; ++kt) {
            const float4* p = (const float4*)(rp + kt * 32);
            float4 x0 = p[0], x1 = p[1];
            uint4 u;
            u.x = cvtpk(x0.x, x0.y); u.y = cvtpk(x0.z, x0.w);
            u.z = cvtpk(x1.x, x1.y); u.w = cvtpk(x1.z, x1.w);
            af[mt][kt] = __builtin_bit_cast(bf16x8, u);
        }
    }

    const float lim = r6 ? 6.0f : 3.4e38f;
#pragma unroll
    for (int nt = 0; nt < 8; ++nt) {
        bf16x8 bfr[4];
#pragma unroll
        for (int kt = 0; kt < 4; ++kt)
            bfr[kt] = __builtin_bit_cast(bf16x8, wp[(kt * 8 + nt) * 64 + lane]);
        float bv = bias[nt * 16 + l16];
        f32x4 acc[2];
#pragma unroll
        for (int mt = 0; mt < 2; ++mt) acc[mt] = (f32x4){bv, bv, bv, bv};
#pragma unroll
        for (int kt = 0; kt < 4; ++kt)
#pragma unroll
            for (int mt = 0; mt < 2; ++mt)
                acc[mt] = __builtin_amdgcn_mfma_f32_16x16x32_bf16(af[mt][kt], bfr[kt], acc[mt], 0, 0, 0);
        // activation + swizzled LDS store (C layout: row=q*4+r, col=l16)
        int colc = m * 128 + nt * 16 + l16;
        int c8 = colc >> 3, c7 = colc & 7;
#pragma unroll
        for (int mt = 0; mt < 2; ++mt) {
#pragma unroll
            for (int r = 0; r < 4; ++r) {
                float v = __builtin_amdgcn_fmed3f(acc[mt][r], 0.0f, lim);
                int row = mh * 32 + mt * 16 + q * 4 + r;
                lds[(row << 9) + ((c8 ^ (row & 7)) << 3) + c7] = f2bf(v);
            }
        }
    }
    __syncthreads();

    // ---- stage 2: h = [inter(0:384)]@W_fr | [inter(0:256,384:512)]@W_fb ----
    const ushort8* wp2   = (w < 4) ? wpfr : wpfb;
    const float*   bias2 = (w < 4) ? b_fr : b_fb;
    const int nb = (w & 3) * 2;          // this wave's 2 n-tiles within its matrix

    f32x4 acc2[2][4];                    // [ntl][mt]
#pragma unroll
    for (int ntl = 0; ntl < 2; ++ntl) {
        float bv = bias2[(nb + ntl) * 16 + l16];
#pragma unroll
        for (int mt = 0; mt < 4; ++mt) acc2[ntl][mt] = (f32x4){bv, bv, bv, bv};
    }

#pragma unroll
    for (int kt = 0; kt < 12; ++kt) {
        int colbase = (w < 4) ? kt * 32 : (kt < 8 ? kt * 32 : 384 + (kt - 8) * 32);
        int c8b = colbase >> 3;
        bf16x8 a[4];
#pragma unroll
        for (int mt = 0; mt < 4; ++mt) {
            int row = mt * 16 + l16;
            a[mt] = *(const bf16x8*)&lds[(row << 9) + (((c8b + q) ^ (row & 7)) << 3)];
        }
        bf16x8 bfr2[2];
#pragma unroll
        for (int ntl = 0; ntl < 2; ++ntl)
            bfr2[ntl] = __builtin_bit_cast(bf16x8, wp2[(kt * 8 + nb + ntl) * 64 + lane]);
#pragma unroll
        for (int ntl = 0; ntl < 2; ++ntl)
#pragma unroll
            for (int mt = 0; mt < 4; ++mt)
                acc2[ntl][mt] = __builtin_amdgcn_mfma_f32_16x16x32_bf16(a[mt], bfr2[ntl], acc2[ntl][mt], 0, 0, 0);
    }
    __syncthreads();   // everyone done reading stage-1 LDS before reuse

    // ---- epilogue A: stage h into LDS (xor-16 bank swizzle) + BN partials --
    const int colb = (w >> 2) * 128 + (w & 3) * 32;
#pragma unroll
    for (int ntl = 0; ntl < 2; ++ntl) {
        int c = colb + ntl * 16 + l16;
        float s = 0.0f, sq = 0.0f;
#pragma unroll
        for (int mt = 0; mt < 4; ++mt) {
#pragma unroll
            for (int r = 0; r < 4; ++r) {
                float v = acc2[ntl][mt][r];
                int row = mt * 16 + q * 4 + r;
                lds[(row << 8) + (c ^ ((row & 4) << 2))] = f2bf(v);
                s += v; sq += v * v;
            }
        }
        s  += __shfl_xor(s, 16);  s  += __shfl_xor(s, 32);
        sq += __shfl_xor(sq, 16); sq += __shfl_xor(sq, 32);
        if (q == 0) {
            pt[(size_t)blk * 512 + c]       = s;
            pt[(size_t)blk * 512 + 256 + c] = sq;
        }
    }
    __syncthreads();

    // ---- epilogue B: coalesced h writes (4 x dwordx4 per thread) -----------
#pragma unroll
    for (int i = 0; i < 4; ++i) {
        int idx  = i * 512 + tid;         // chunk of 8 ushorts
        int row  = idx >> 5;
        int cb   = (idx & 31) * 8;
        int phys = (row << 8) + (cb ^ ((row & 4) << 2));
        uint4 v = *(const uint4*)&lds[phys];
        *(uint4*)(hout + (((size_t)(e0 + row)) << 8) + cb) = v;
    }
}

// ---------------------------------------------------------------------------
// K2a: coalesced partial reduction of pt rows. Block b sums 64 rows for all
// 512 columns (threads read consecutive floats). pt2[b*512 + t].
// ---------------------------------------------------------------------------
__global__ __launch_bounds__(256) void k2a_reduce(
        const float* __restrict__ pt, float* __restrict__ pt2)
{
    int b = blockIdx.x, t = threadIdx.x;
    const float* base = pt + (size_t)b * 64 * 512;
    float s0 = 0.0f, s1 = 0.0f;
    for (int r = 0; r < 64; ++r) {
        s0 += base[r * 512 + t];
        s1 += base[r * 512 + 256 + t];
    }
    pt2[b * 512 + t]       = s0;
    pt2[b * 512 + 256 + t] = s1;
}

// ---------------------------------------------------------------------------
// K2b: finalize BN affine (scale, shift) from 64 partial rows.
// ---------------------------------------------------------------------------
__global__ __launch_bounds__(256) void k2b_stats(
        const float* __restrict__ pt2, const float* __restrict__ gamma,
        const float* __restrict__ beta, float* __restrict__ stats)
{
    int c = threadIdx.x;   // single block, 256 threads
    float S = 0.0f, Q = 0.0f;
    for (int i = 0; i < 64; ++i) {
        S += pt2[i * 512 + c];
        Q += pt2[i * 512 + 256 + c];
    }
    float mu  = S / (float)E_TOT;
    float var = Q / (float)E_TOT - mu * mu;
    float sc  = gamma[c] * rsqrtf(var + BN_EPS);
    stats[c]       = sc;
    stats[256 + c] = beta[c] - mu * sc;
}

// ---------------------------------------------------------------------------
// K3: per-graph BN-apply + relu + mean-pool + MLP(257->16->1) -> out[g]
// Lanes load uint4 (8 cols); 8 rows in flight per block iteration.
// ---------------------------------------------------------------------------
__global__ __launch_bounds__(256) void k3_pool(
        const unsigned short* __restrict__ h, const int* __restrict__ gidx,
        const float* __restrict__ ref, const float* __restrict__ stats,
        const float* __restrict__ W1, const float* __restrict__ b1,
        const float* __restrict__ W2, const float* __restrict__ b2,
        float* __restrict__ out)
{
    int g = blockIdx.x, tid = threadIdx.x;
    int w = tid >> 6, lane = tid & 63;
    // lower_bound(g), lower_bound(g+1) on sorted graph_idx
    int lo = 0, hi = E_TOT;
    while (lo < hi) { int m = (lo + hi) >> 1; if (gidx[m] < g) lo = m + 1; else hi = m; }
    int start = lo;
    hi = E_TOT;
    while (lo < hi) { int m = (lo + hi) >> 1; if (gidx[m] < g + 1) lo = m + 1; else hi = m; }
    int end = lo;

    int half = lane >> 5;
    int c0   = (lane & 31) * 8;
    float sc[8], sh[8], acc[8];
#pragma unroll
    for (int j = 0; j < 8; ++j) {
        sc[j] = stats[c0 + j]; sh[j] = stats[256 + c0 + j]; acc[j] = 0.0f;
    }

    for (int r = start + w * 2 + half; r < end; r += 8) {
        uint4 v = *(const uint4*)(h + (((size_t)r) << 8) + c0);
        unsigned u[4] = {v.x, v.y, v.z, v.w};
#pragma unroll
        for (int j = 0; j < 4; ++j) {
            float f0 = bf2f((unsigned short)(u[j] & 0xffff));
            float f1 = bf2f((unsigned short)(u[j] >> 16));
            acc[2 * j]     += fmaxf(fmaf(f0, sc[2 * j],     sh[2 * j]),     0.0f);
            acc[2 * j + 1] += fmaxf(fmaf(f1, sc[2 * j + 1], sh[2 * j + 1]), 0.0f);
        }
    }
#pragma unroll
    for (int j = 0; j < 8; ++j) acc[j] += __shfl_xor(acc[j], 32);

    __shared__ float part[4 * 256];
    __shared__ float sp[256];
    if (half == 0) {
#pragma unroll
        for (int j = 0; j < 8; ++j) part[w * 256 + c0 + j] = acc[j];
    }
    __syncthreads();

    int n = end - start;
    float inv = 1.0f / fmaxf((float)n, 1.0f);
    sp[tid] = (part[tid] + part[256 + tid] + part[512 + tid] + part[768 + tid]) * inv;
    __syncthreads();

    if (tid < 16) {
        float z = b1[tid] + ref[g] * W1[256 * 16 + tid];
        for (int c = 0; c < 256; ++c) z = fmaf(sp[c], W1[c * 16 + tid], z);
        z = fmaxf(z, 0.0f);
        float t = z * W2[tid];
        t += __shfl_xor(t, 1); t += __shfl_xor(t, 2);
        t += __shfl_xor(t, 4); t += __shfl_xor(t, 8);
        if (tid == 0) out[g] = fmaxf(t + b2[0], 0.0f);
    }
}

// ---------------------------------------------------------------------------
// Workspace layout (bytes):
//   [0)         packed bf16 weights: 147456 * 2        = 294912
//   [294912)    h: E*256 bf16                          = 134217728
//   [134512640) pt: 4096*512 f32 partials              = 8388608
//   [142901248) pt2: 64*512 f32 partials               = 131072
//   [151289856) stats: 512 f32                         = 2048
// ---------------------------------------------------------------------------
extern "C" void kernel_launch(void* const* d_in, const int* in_sizes, int n_in,
                              void* d_out, int out_size, void* d_ws, size_t ws_size,
                              hipStream_t stream)
{
    (void)in_sizes; (void)n_in; (void)out_size; (void)ws_size;
    const float* atom  = (const float*)d_in[0];
    const float* rdf   = (const float*)d_in[1];
    const float* bdf   = (const float*)d_in[2];
    const int*   gidx  = (const int*)d_in[6];
    const float* ref   = (const float*)d_in[7];
    const float* Wea   = (const float*)d_in[8];  const float* bea = (const float*)d_in[9];
    const float* Wer   = (const float*)d_in[10]; const float* ber = (const float*)d_in[11];
    const float* Web   = (const float*)d_in[12]; const float* beb = (const float*)d_in[13];
    const float* Wfr   = (const float*)d_in[14]; const float* bfr = (const float*)d_in[15];
    const float* Wfb   = (const float*)d_in[16]; const float* bfb = (const float*)d_in[17];
    const float* gamma = (const float*)d_in[18]; const float* beta = (const float*)d_in[19];
    const float* W1    = (const float*)d_in[20]; const float* b1  = (const float*)d_in[21];
    const float* W2    = (const float*)d_in[22]; const float* b2  = (const float*)d_in[23];

    char* ws = (char*)d_ws;
    unsigned short* wpack = (unsigned short*)ws;
    unsigned short* h     = (unsigned short*)(ws + 294912);
    float*          pt    = (float*)(ws + 134512640);
    float*          pt2   = (float*)(ws + 142901248);
    float*          stats = (float*)(ws + 151289856);

    k0_pack<<<576, 256, 0, stream>>>(Wea, Wer, Web, Wfr, Wfb, wpack);
    k1_edges<<<NB1, 512, 0, stream>>>(atom, rdf, bdf, bea, ber, beb, bfr, bfb,
            (const ushort8*)wpack,
            (const ushort8*)(wpack + 16384),
            (const ushort8*)(wpack + 32768),
            (const ushort8*)(wpack + 49152),
            (const ushort8*)(wpack + 98304),
            h, pt);
    k2a_reduce<<<64, 256, 0, stream>>>(pt, pt2);
    k2b_stats<<<1, 256, 0, stream>>>(pt2, gamma, beta, stats);
    k3_pool<<<G_TOT, 256, 0, stream>>>(h, gidx, ref, stats, W1, b1, W2, b2, (float*)d_out);
}

// Round 5
// 660.352 us; speedup vs baseline: 1.1496x; 1.0128x over previous
//
#include <hip/hip_runtime.h>

#define E_TOT 262144
#define EPB   64        // edges per K1 block
#define NB1   4096      // E_TOT / EPB
#define G_TOT 1024
#define BN_EPS 1e-5f

using f32x4   = __attribute__((ext_vector_type(4))) float;
using bf16x8  = __attribute__((ext_vector_type(8))) __bf16;
using ushort8 = __attribute__((ext_vector_type(8))) unsigned short;

static __device__ __forceinline__ unsigned short f2bf(float x) {
    union { float f; unsigned u; } v; v.f = x;
    unsigned r = v.u + 0x7FFFu + ((v.u >> 16) & 1u);   // RTNE
    return (unsigned short)(r >> 16);
}
static __device__ __forceinline__ float bf2f(unsigned short h) {
    union { unsigned u; float f; } v; v.u = ((unsigned)h) << 16;
    return v.f;
}
// packed f32x2 -> bf16x2 (RTNE), lo in bits[15:0]
static __device__ __forceinline__ unsigned cvtpk(float lo, float hi) {
    unsigned r;
    asm("v_cvt_pk_bf16_f32 %0, %1, %2" : "=v"(r) : "v"(lo), "v"(hi));
    return r;
}

// ---------------------------------------------------------------------------
// K0: pack 5 weight matrices (f32 [K][128] row-major) into bf16 MFMA
// B-fragment order for mfma_f32_16x16x32_bf16 (16B contiguous per lane).
// ---------------------------------------------------------------------------
__global__ __launch_bounds__(256) void k0_pack(
        const float* __restrict__ wea, const float* __restrict__ wer,
        const float* __restrict__ web, const float* __restrict__ wfr,
        const float* __restrict__ wfb, unsigned short* __restrict__ out)
{
    int idx = blockIdx.x * 256 + threadIdx.x;   // 0 .. 147455
    const float* src; unsigned short* dst; int li;
    if      (idx < 16384) { src = wea; dst = out;          li = idx;          }
    else if (idx < 32768) { src = wer; dst = out + 16384;  li = idx - 16384;  }
    else if (idx < 49152) { src = web; dst = out + 32768;  li = idx - 32768;  }
    else if (idx < 98304) { src = wfr; dst = out + 49152;  li = idx - 49152;  }
    else                  { src = wfb; dst = out + 98304;  li = idx - 98304;  }
    int j    = li & 7;
    int lane = (li >> 3) & 63;
    int tile = li >> 9;
    int nt = tile & 7, kt = tile >> 3;
    int k = kt * 32 + (lane >> 4) * 8 + j;
    int n = nt * 16 + (lane & 15);
    dst[li] = f2bf(src[k * 128 + n]);
}

// ---------------------------------------------------------------------------
// K_bounds: segment boundaries of sorted gidx -> bounds[0..G]
// bounds[g] = lower_bound(gidx, g); bounds[G] = E.
// ---------------------------------------------------------------------------
__global__ __launch_bounds__(256) void k_bounds(
        const int* __restrict__ gidx, int* __restrict__ bounds)
{
    int e = blockIdx.x * 256 + threadIdx.x;
    if (e >= E_TOT) return;
    int ge = gidx[e];
    if (e == 0) {
        for (int g = 0; g <= ge; ++g) bounds[g] = 0;
    } else {
        int gp = gidx[e - 1];
        for (int g = gp + 1; g <= ge; ++g) bounds[g] = e;
    }
    if (e == E_TOT - 1) {
        for (int g = ge + 1; g <= G_TOT; ++g) bounds[g] = E_TOT;
    }
}

// ---------------------------------------------------------------------------
// K1: fused edge MLP. 64 edges/block, 8 waves (512 thr), 64 KB LDS.
// 2 blocks/CU -> 16 waves/CU (4/SIMD); waves_per_eu pinned 4,4 so the
// scheduler uses the full 128-VGPR budget for software pipelining.
// Stage 1: wave w -> matrix m=w>>1, row-half mh=w&1; B-fragments 1-deep
//          register-pipelined across the nt loop.
// Stage 2: wave w owns 2 n-tiles over K=384; LDS A-frags + global B-frags
//          1-deep register-pipelined; kt=0 B prefetched before the barrier.
// ---------------------------------------------------------------------------
__global__ __launch_bounds__(512)
__attribute__((amdgpu_waves_per_eu(4, 4)))
void k1_edges(
        const float* __restrict__ atom, const float* __restrict__ rdf,
        const float* __restrict__ bdf,
        const float* __restrict__ b_ea, const float* __restrict__ b_er,
        const float* __restrict__ b_eb, const float* __restrict__ b_fr,
        const float* __restrict__ b_fb,
        const ushort8* __restrict__ wpea, const ushort8* __restrict__ wper,
        const ushort8* __restrict__ wpeb, const ushort8* __restrict__ wpfr,
        const ushort8* __restrict__ wpfb,
        unsigned short* __restrict__ hout, float* __restrict__ pt)
{
    __shared__ unsigned short lds[EPB * 512];   // 64 KB

    const int tid  = threadIdx.x;
    const int w    = tid >> 6;        // 0..7
    const int lane = tid & 63;
    const int l16  = lane & 15;
    const int q    = lane >> 4;
    const int blk  = blockIdx.x;
    const int e0   = blk * EPB;

    // ---- stage 1: matrix m = w>>1, row-half mh = w&1 -----------------------
    const int m  = w >> 1;
    const int mh = w & 1;
    const float* src; int stride; const ushort8* wp; const float* bias; bool r6;
    if      (m == 0) { src = atom;        stride = 256; wp = wpea; bias = b_ea; r6 = false; }
    else if (m == 1) { src = atom + 128;  stride = 256; wp = wpea; bias = b_ea; r6 = false; }
    else if (m == 2) { src = rdf;         stride = 128; wp = wper; bias = b_er; r6 = true;  }
    else             { src = bdf;         stride = 128; wp = wpeb; bias = b_eb; r6 = true;  }

    bf16x8 af[2][4];   // [m-tile][k-tile] A fragments: A[row=mh*32+mt*16+l16][k=q*8+j]
#pragma unroll
    for (int mt = 0; mt < 2; ++mt) {
        const float* rp = src + (size_t)(e0 + mh * 32 + mt * 16 + l16) * stride + q * 8;
#pragma unroll
        for (int kt = 0; kt < 4; ++kt) {
            const float4* p = (const float4*)(rp + kt * 32);
            float4 x0 = p[0], x1 = p[1];
            uint4 u;
            u.x = cvtpk(x0.x, x0.y); u.y = cvtpk(x0.z, x0.w);
            u.z = cvtpk(x1.x, x1.y); u.w = cvtpk(x1.z, x1.w);
            af[mt][kt] = __builtin_bit_cast(bf16x8, u);
        }
    }

    const float lim = r6 ? 6.0f : 3.4e38f;
    // 1-deep pipelined B-fragments across nt
    bf16x8 bcur[4], bnxt[4];
#pragma unroll
    for (int kt = 0; kt < 4; ++kt)
        bcur[kt] = __builtin_bit_cast(bf16x8, wp[(kt * 8 + 0) * 64 + lane]);
#pragma unroll
    for (int nt = 0; nt < 8; ++nt) {
        if (nt < 7) {
#pragma unroll
            for (int kt = 0; kt < 4; ++kt)
                bnxt[kt] = __builtin_bit_cast(bf16x8, wp[(kt * 8 + nt + 1) * 64 + lane]);
        }
        float bv = bias[nt * 16 + l16];
        f32x4 acc[2];
#pragma unroll
        for (int mt = 0; mt < 2; ++mt) acc[mt] = (f32x4){bv, bv, bv, bv};
#pragma unroll
        for (int kt = 0; kt < 4; ++kt)
#pragma unroll
            for (int mt = 0; mt < 2; ++mt)
                acc[mt] = __builtin_amdgcn_mfma_f32_16x16x32_bf16(af[mt][kt], bcur[kt], acc[mt], 0, 0, 0);
        // activation + swizzled LDS store (C layout: row=q*4+r, col=l16)
        int colc = m * 128 + nt * 16 + l16;
        int c8 = colc >> 3, c7 = colc & 7;
#pragma unroll
        for (int mt = 0; mt < 2; ++mt) {
#pragma unroll
            for (int r = 0; r < 4; ++r) {
                float v = __builtin_amdgcn_fmed3f(acc[mt][r], 0.0f, lim);
                int row = mh * 32 + mt * 16 + q * 4 + r;
                lds[(row << 9) + ((c8 ^ (row & 7)) << 3) + c7] = f2bf(v);
            }
        }
#pragma unroll
        for (int kt = 0; kt < 4; ++kt) bcur[kt] = bnxt[kt];
    }

    // ---- stage 2: h = [inter(0:384)]@W_fr | [inter(0:256,384:512)]@W_fb ----
    const ushort8* wp2   = (w < 4) ? wpfr : wpfb;
    const float*   bias2 = (w < 4) ? b_fr : b_fb;
    const int nb = (w & 3) * 2;          // this wave's 2 n-tiles within its matrix

    // prefetch kt=0 global B-fragments BEFORE the barrier (hide L2 latency)
    bf16x8 b2cur[2], b2nxt[2];
#pragma unroll
    for (int ntl = 0; ntl < 2; ++ntl)
        b2cur[ntl] = __builtin_bit_cast(bf16x8, wp2[(0 * 8 + nb + ntl) * 64 + lane]);

    __syncthreads();

    f32x4 acc2[2][4];                    // [ntl][mt]
#pragma unroll
    for (int ntl = 0; ntl < 2; ++ntl) {
        float bv = bias2[(nb + ntl) * 16 + l16];
#pragma unroll
        for (int mt = 0; mt < 4; ++mt) acc2[ntl][mt] = (f32x4){bv, bv, bv, bv};
    }

    // kt=0 LDS A-fragments (colbase 0 for all waves)
    bf16x8 a2cur[4], a2nxt[4];
#pragma unroll
    for (int mt = 0; mt < 4; ++mt) {
        int row = mt * 16 + l16;
        a2cur[mt] = *(const bf16x8*)&lds[(row << 9) + ((q ^ (row & 7)) << 3)];
    }

#pragma unroll
    for (int kt = 0; kt < 12; ++kt) {
        if (kt < 11) {
            int kt1 = kt + 1;
            int colbase = (w < 4) ? kt1 * 32 : (kt1 < 8 ? kt1 * 32 : 384 + (kt1 - 8) * 32);
            int c8b = colbase >> 3;
#pragma unroll
            for (int mt = 0; mt < 4; ++mt) {
                int row = mt * 16 + l16;
                a2nxt[mt] = *(const bf16x8*)&lds[(row << 9) + (((c8b + q) ^ (row & 7)) << 3)];
            }
#pragma unroll
            for (int ntl = 0; ntl < 2; ++ntl)
                b2nxt[ntl] = __builtin_bit_cast(bf16x8, wp2[(kt1 * 8 + nb + ntl) * 64 + lane]);
        }
#pragma unroll
        for (int ntl = 0; ntl < 2; ++ntl)
#pragma unroll
            for (int mt = 0; mt < 4; ++mt)
                acc2[ntl][mt] = __builtin_amdgcn_mfma_f32_16x16x32_bf16(a2cur[mt], b2cur[ntl], acc2[ntl][mt], 0, 0, 0);
#pragma unroll
        for (int mt = 0; mt < 4; ++mt) a2cur[mt] = a2nxt[mt];
#pragma unroll
        for (int ntl = 0; ntl < 2; ++ntl) b2cur[ntl] = b2nxt[ntl];
    }
    __syncthreads();   // everyone done reading stage-1 LDS before reuse

    // ---- epilogue A: stage h into LDS (xor-16 bank swizzle) + BN partials --
    const int colb = (w >> 2) * 128 + (w & 3) * 32;
#pragma unroll
    for (int ntl = 0; ntl < 2; ++ntl) {
        int c = colb + ntl * 16 + l16;
        float s = 0.0f, sq = 0.0f;
#pragma unroll
        for (int mt = 0; mt < 4; ++mt) {
#pragma unroll
            for (int r = 0; r < 4; ++r) {
                float v = acc2[ntl][mt][r];
                int row = mt * 16 + q * 4 + r;
                lds[(row << 8) + (c ^ ((row & 4) << 2))] = f2bf(v);
                s += v; sq += v * v;
            }
        }
        s  += __shfl_xor(s, 16);  s  += __shfl_xor(s, 32);
        sq += __shfl_xor(sq, 16); sq += __shfl_xor(sq, 32);
        if (q == 0) {
            pt[(size_t)blk * 512 + c]       = s;
            pt[(size_t)blk * 512 + 256 + c] = sq;
        }
    }
    __syncthreads();

    // ---- epilogue B: coalesced h writes (4 x dwordx4 per thread) -----------
#pragma unroll
    for (int i = 0; i < 4; ++i) {
        int idx  = i * 512 + tid;         // chunk of 8 ushorts
        int row  = idx >> 5;
        int cb   = (idx & 31) * 8;
        int phys = (row << 8) + (cb ^ ((row & 4) << 2));
        uint4 v = *(const uint4*)&lds[phys];
        *(uint4*)(hout + (((size_t)(e0 + row)) << 8) + cb) = v;
    }
}

// ---------------------------------------------------------------------------
// K2a: coalesced partial reduction of pt rows. Block b sums 64 rows for all
// 512 columns (threads read consecutive floats). pt2[b*512 + t].
// ---------------------------------------------------------------------------
__global__ __launch_bounds__(256) void k2a_reduce(
        const float* __restrict__ pt, float* __restrict__ pt2)
{
    int b = blockIdx.x, t = threadIdx.x;
    const float* base = pt + (size_t)b * 64 * 512;
    float s0 = 0.0f, s1 = 0.0f;
    for (int r = 0; r < 64; ++r) {
        s0 += base[r * 512 + t];
        s1 += base[r * 512 + 256 + t];
    }
    pt2[b * 512 + t]       = s0;
    pt2[b * 512 + 256 + t] = s1;
}

// ---------------------------------------------------------------------------
// K2b: finalize BN affine (scale, shift) from 64 partial rows.
// ---------------------------------------------------------------------------
__global__ __launch_bounds__(256) void k2b_stats(
        const float* __restrict__ pt2, const float* __restrict__ gamma,
        const float* __restrict__ beta, float* __restrict__ stats)
{
    int c = threadIdx.x;   // single block, 256 threads
    float S = 0.0f, Q = 0.0f;
    for (int i = 0; i < 64; ++i) {
        S += pt2[i * 512 + c];
        Q += pt2[i * 512 + 256 + c];
    }
    float mu  = S / (float)E_TOT;
    float var = Q / (float)E_TOT - mu * mu;
    float sc  = gamma[c] * rsqrtf(var + BN_EPS);
    stats[c]       = sc;
    stats[256 + c] = beta[c] - mu * sc;
}

// ---------------------------------------------------------------------------
// K3: per-graph BN-apply + relu + mean-pool + MLP(257->16->1) -> out[g]
// bounds[] precomputed (no binary search); W1 in LDS; MLP tail parallel.
// ---------------------------------------------------------------------------
__global__ __launch_bounds__(256) void k3_pool(
        const unsigned short* __restrict__ h, const int* __restrict__ bounds,
        const float* __restrict__ ref, const float* __restrict__ stats,
        const float* __restrict__ W1, const float* __restrict__ b1,
        const float* __restrict__ W2, const float* __restrict__ b2,
        float* __restrict__ out)
{
    __shared__ float w1l[257 * 16];     // 16448 B
    __shared__ float part[4 * 256];
    __shared__ float sp[256];
    __shared__ float pz[256];

    int g = blockIdx.x, tid = threadIdx.x;
    int w = tid >> 6, lane = tid & 63;

    // preload W1 (coalesced; covered by the barrier below)
    for (int i = tid; i < 257 * 16; i += 256) w1l[i] = W1[i];

    int start = bounds[g], end = bounds[g + 1];

    int half = lane >> 5;
    int c0   = (lane & 31) * 8;
    float sc[8], sh[8], acc[8];
#pragma unroll
    for (int j = 0; j < 8; ++j) {
        sc[j] = stats[c0 + j]; sh[j] = stats[256 + c0 + j]; acc[j] = 0.0f;
    }

    for (int r = start + w * 2 + half; r < end; r += 8) {
        uint4 v = *(const uint4*)(h + (((size_t)r) << 8) + c0);
        unsigned u[4] = {v.x, v.y, v.z, v.w};
#pragma unroll
        for (int j = 0; j < 4; ++j) {
            float f0 = bf2f((unsigned short)(u[j] & 0xffff));
            float f1 = bf2f((unsigned short)(u[j] >> 16));
            acc[2 * j]     += fmaxf(fmaf(f0, sc[2 * j],     sh[2 * j]),     0.0f);
            acc[2 * j + 1] += fmaxf(fmaf(f1, sc[2 * j + 1], sh[2 * j + 1]), 0.0f);
        }
    }
#pragma unroll
    for (int j = 0; j < 8; ++j) acc[j] += __shfl_xor(acc[j], 32);

    if (half == 0) {
#pragma unroll
        for (int j = 0; j < 8; ++j) part[w * 256 + c0 + j] = acc[j];
    }
    __syncthreads();

    int n = end - start;
    float inv = 1.0f / fmaxf((float)n, 1.0f);
    sp[tid] = (part[tid] + part[256 + tid] + part[512 + tid] + part[768 + tid]) * inv;
    __syncthreads();

    // parallel 257->16: thread (chunk, j) does 16 of the 256 k-terms
    {
        int j = tid & 15, chunk = tid >> 4;
        float z = 0.0f;
#pragma unroll
        for (int c = 0; c < 16; ++c)
            z = fmaf(sp[chunk * 16 + c], w1l[(chunk * 16 + c) * 16 + j], z);
        pz[tid] = z;
    }
    __syncthreads();

    if (tid < 16) {
        float z = b1[tid] + ref[g] * w1l[256 * 16 + tid];
#pragma unroll
        for (int i = 0; i < 16; ++i) z += pz[i * 16 + tid];
        z = fmaxf(z, 0.0f);
        float t = z * W2[tid];
        t += __shfl_xor(t, 1); t += __shfl_xor(t, 2);
        t += __shfl_xor(t, 4); t += __shfl_xor(t, 8);
        if (tid == 0) out[g] = fmaxf(t + b2[0], 0.0f);
    }
}

// ---------------------------------------------------------------------------
// Workspace layout (bytes):
//   [0)         packed bf16 weights: 147456 * 2        = 294912
//   [294912)    h: E*256 bf16                          = 134217728
//   [134512640) pt: 4096*512 f32 partials              = 8388608
//   [142901248) pt2: 64*512 f32 partials               = 131072
//   [143032320) bounds: (G+1) int32                    = 4100
//   [151289856) stats: 512 f32                         = 2048
// ---------------------------------------------------------------------------
extern "C" void kernel_launch(void* const* d_in, const int* in_sizes, int n_in,
                              void* d_out, int out_size, void* d_ws, size_t ws_size,
                              hipStream_t stream)
{
    (void)in_sizes; (void)n_in; (void)out_size; (void)ws_size;
    const float* atom  = (const float*)d_in[0];
    const float* rdf   = (const float*)d_in[1];
    const float* bdf   = (const float*)d_in[2];
    const int*   gidx  = (const int*)d_in[6];
    const float* ref   = (const float*)d_in[7];
    const float* Wea   = (const float*)d_in[8];  const float* bea = (const float*)d_in[9];
    const float* Wer   = (const float*)d_in[10]; const float* ber = (const float*)d_in[11];
    const float* Web   = (const float*)d_in[12]; const float* beb = (const float*)d_in[13];
    const float* Wfr   = (const float*)d_in[14]; const float* bfr = (const float*)d_in[15];
    const float* Wfb   = (const float*)d_in[16]; const float* bfb = (const float*)d_in[17];
    const float* gamma = (const float*)d_in[18]; const float* beta = (const float*)d_in[19];
    const float* W1    = (const float*)d_in[20]; const float* b1  = (const float*)d_in[21];
    const float* W2    = (const float*)d_in[22]; const float* b2  = (const float*)d_in[23];

    char* ws = (char*)d_ws;
    unsigned short* wpack  = (unsigned short*)ws;
    unsigned short* h      = (unsigned short*)(ws + 294912);
    float*          pt     = (float*)(ws + 134512640);
    float*          pt2    = (float*)(ws + 142901248);
    int*            bounds = (int*)(ws + 143032320);
    float*          stats  = (float*)(ws + 151289856);

    k0_pack<<<576, 256, 0, stream>>>(Wea, Wer, Web, Wfr, Wfb, wpack);
    k_bounds<<<1024, 256, 0, stream>>>(gidx, bounds);
    k1_edges<<<NB1, 512, 0, stream>>>(atom, rdf, bdf, bea, ber, beb, bfr, bfb,
            (const ushort8*)wpack,
            (const ushort8*)(wpack + 16384),
            (const ushort8*)(wpack + 32768),
            (const ushort8*)(wpack + 49152),
            (const ushort8*)(wpack + 98304),
            h, pt);
    k2a_reduce<<<64, 256, 0, stream>>>(pt, pt2);
    k2b_stats<<<1, 256, 0, stream>>>(pt2, gamma, beta, stats);
    k3_pool<<<G_TOT, 256, 0, stream>>>(h, bounds, ref, stats, W1, b1, W2, b2, (float*)d_out);
}